// Round 1
// baseline (165.129 us; speedup 1.0000x reference)
//
#include <hip/hip_runtime.h>
#include <math.h>

#define BB 4
#define NN 512
#define F_IN 256
#define F_OUT 128
#define HH 64
#define NEG_INF_F -1e30f
#define LALPHA 0.01f

// ---- float atomic-max encoding (order-preserving uint mapping) ----
__device__ __forceinline__ unsigned fenc(float f) {
    unsigned b = __float_as_uint(f);
    return (b & 0x80000000u) ? ~b : (b | 0x80000000u);
}
__device__ __forceinline__ float fdec(unsigned u) {
    return __uint_as_float((u & 0x80000000u) ? (u ^ 0x80000000u) : ~u);
}

// K1: h = x @ W^T + bW ; hi = h @ A1a^T ; hj = h @ A1b^T
// grid = B*N blocks, 128 threads (one per F_OUT column)
__global__ __launch_bounds__(128) void k_proj(
    const float* __restrict__ x, const float* __restrict__ W,
    const float* __restrict__ bW, const float* __restrict__ A1,
    float* __restrict__ h, float* __restrict__ hi, float* __restrict__ hj,
    unsigned* __restrict__ maxenc, float* __restrict__ sums)
{
    const int row = blockIdx.x;           // b*N + n
    const int tid = threadIdx.x;

    // init softmax stats (read only by later kernels)
    if (row == 0 && tid < BB) { maxenc[tid] = 0u; sums[tid] = 0.0f; }

    __shared__ float xs[F_IN];
    xs[tid]       = x[row * F_IN + tid];
    xs[tid + 128] = x[row * F_IN + 128 + tid];
    __syncthreads();

    float acc = bW[tid];
    const float* wr = W + tid * F_IN;
    #pragma unroll 8
    for (int f = 0; f < F_IN; ++f) acc = fmaf(xs[f], wr[f], acc);
    h[row * F_OUT + tid] = acc;

    __shared__ float hs[F_OUT];
    hs[tid] = acc;
    __syncthreads();

    const int t = tid & 63;
    const float* ar = A1 + t * (2 * F_OUT) + ((tid >= 64) ? F_OUT : 0);
    float acc2 = 0.0f;
    #pragma unroll 8
    for (int o = 0; o < F_OUT; ++o) acc2 = fmaf(hs[o], ar[o], acc2);
    if (tid < 64) hi[row * HH + t] = acc2;
    else          hj[row * HH + t] = acc2;
}

// K2: e[b,i,j] = leakyrelu(sum_h relu(hi+hj+b1)*A2 + b2); mask with adj; batch max
// grid = B*N blocks (one per (b,i) row), 256 threads
__global__ __launch_bounds__(256) void k_scores(
    const float* __restrict__ hi, const float* __restrict__ hj,
    const float* __restrict__ b1, const float* __restrict__ A2,
    const float* __restrict__ b2, const float* __restrict__ adj,
    float* __restrict__ e, unsigned* __restrict__ maxenc)
{
    const int row = blockIdx.x;    // b*N + i
    const int b   = row >> 9;      // row / 512
    const int tid = threadIdx.x;

    __shared__ float his[HH], b1s[HH], a2s[HH];
    if (tid < HH) {
        his[tid] = hi[row * HH + tid];
        b1s[tid] = b1[tid];
        a2s[tid] = A2[tid];
    }
    __syncthreads();

    const float b2v = b2[0];
    float lmax = -INFINITY;
    const float* adjr = adj + (size_t)row * NN;
    float*       er   = e   + (size_t)row * NN;
    const float* hjb  = hj  + (size_t)b * NN * HH;

    for (int j = tid; j < NN; j += 256) {
        const float* hjr = hjb + j * HH;
        float s = 0.0f;
        #pragma unroll 8
        for (int k = 0; k < HH; ++k) {
            float z = his[k] + hjr[k] + b1s[k];
            z = fmaxf(z, 0.0f);
            s = fmaf(z, a2s[k], s);
        }
        s += b2v;
        s = (s >= 0.0f) ? s : LALPHA * s;
        const float a = adjr[j];
        const float lg = (a != 0.0f) ? s : NEG_INF_F;
        er[j] = lg;
        lmax = fmaxf(lmax, lg);
    }

    // block max reduce (wave64 shfl + LDS)
    for (int off = 32; off; off >>= 1) lmax = fmaxf(lmax, __shfl_down(lmax, off, 64));
    __shared__ float wmax[4];
    if ((tid & 63) == 0) wmax[tid >> 6] = lmax;
    __syncthreads();
    if (tid == 0) {
        float m = fmaxf(fmaxf(wmax[0], wmax[1]), fmaxf(wmax[2], wmax[3]));
        atomicMax(maxenc + b, fenc(m));
    }
}

// K3: w = exp(e - max_b), per-row partial sum -> atomicAdd per batch
// grid = B*N blocks, 256 threads
__global__ __launch_bounds__(256) void k_exp(
    float* __restrict__ e, const unsigned* __restrict__ maxenc,
    float* __restrict__ sums)
{
    const int row = blockIdx.x;
    const int b   = row >> 9;
    const int tid = threadIdx.x;
    const float m = fdec(maxenc[b]);

    float* er = e + (size_t)row * NN;
    float ls = 0.0f;
    for (int j = tid; j < NN; j += 256) {
        float w = expf(er[j] - m);   // masked entries: expf(-1e30 - m) == 0
        er[j] = w;
        ls += w;
    }
    for (int off = 32; off; off >>= 1) ls += __shfl_down(ls, off, 64);
    __shared__ float wsum[4];
    if ((tid & 63) == 0) wsum[tid >> 6] = ls;
    __syncthreads();
    if (tid == 0) atomicAdd(sums + b, wsum[0] + wsum[1] + wsum[2] + wsum[3]);
}

// K4: out[b,i,o] = elu( (1/S_b) * sum_j w[b,i,j] * h[b,j,o] )
// grid = B * (N/8) blocks (8 i-rows per block), 128 threads (one per o)
__global__ __launch_bounds__(128) void k_aggregate(
    const float* __restrict__ w, const float* __restrict__ h,
    const float* __restrict__ sums, float* __restrict__ out)
{
    const int b   = blockIdx.x >> 6;          // 64 tiles per batch
    const int i0  = (blockIdx.x & 63) * 8;
    const int tid = threadIdx.x;              // o
    const float invS = 1.0f / sums[b];

    float acc[8] = {0,0,0,0,0,0,0,0};
    __shared__ float wls[8][64];
    const float* wb = w + ((size_t)b * NN + i0) * NN;
    const float* hb = h + (size_t)b * NN * F_OUT;

    for (int j0 = 0; j0 < NN; j0 += 64) {
        #pragma unroll
        for (int k = 0; k < 4; ++k) {
            int idx = tid + k * 128;
            wls[idx >> 6][idx & 63] = wb[(idx >> 6) * NN + j0 + (idx & 63)];
        }
        __syncthreads();
        #pragma unroll 4
        for (int jj = 0; jj < 64; ++jj) {
            float hv = hb[(j0 + jj) * F_OUT + tid];
            #pragma unroll
            for (int r = 0; r < 8; ++r) acc[r] = fmaf(wls[r][jj], hv, acc[r]);
        }
        __syncthreads();
    }

    #pragma unroll
    for (int r = 0; r < 8; ++r) {
        float f = acc[r] * invS;
        out[((size_t)b * NN + i0 + r) * F_OUT + tid] = (f > 0.0f) ? f : expm1f(f);
    }
}

extern "C" void kernel_launch(void* const* d_in, const int* in_sizes, int n_in,
                              void* d_out, int out_size, void* d_ws, size_t ws_size,
                              hipStream_t stream) {
    const float* x   = (const float*)d_in[0];
    const float* adj = (const float*)d_in[1];
    const float* W   = (const float*)d_in[2];
    const float* bW  = (const float*)d_in[3];
    const float* A1  = (const float*)d_in[4];
    const float* b1  = (const float*)d_in[5];
    const float* A2  = (const float*)d_in[6];
    const float* b2  = (const float*)d_in[7];
    float* out = (float*)d_out;

    // workspace layout (floats)
    float* ws  = (float*)d_ws;
    float* h   = ws;                         // B*N*F_OUT = 262144
    float* hi  = h  + BB * NN * F_OUT;       // B*N*H     = 131072
    float* hj  = hi + BB * NN * HH;          // B*N*H     = 131072
    float* e   = hj + BB * NN * HH;          // B*N*N     = 1048576
    unsigned* maxenc = (unsigned*)(e + (size_t)BB * NN * NN);  // 4
    float* sums = (float*)(maxenc + BB);                       // 4

    k_proj     <<<BB * NN,       128, 0, stream>>>(x, W, bW, A1, h, hi, hj, maxenc, sums);
    k_scores   <<<BB * NN,       256, 0, stream>>>(hi, hj, b1, A2, b2, adj, e, maxenc);
    k_exp      <<<BB * NN,       256, 0, stream>>>(e, maxenc, sums);
    k_aggregate<<<BB * (NN / 8), 128, 0, stream>>>(e, h, sums, out);
}

// Round 2
// 70.824 us; speedup vs baseline: 2.3316x; 2.3316x over previous
//
#include <hip/hip_runtime.h>
#include <math.h>

#define BB 4
#define NN 512
#define F_IN 256
#define F_OUT 128
#define HH 64
#define NEG_INF_F -1e30f
#define LALPHA 0.01f

// K1: h = x@W^T + bW ; hi' = h@A1a^T + b1 ; hjT[b][k][n] = (h@A1b^T)^T
// 8 rows per block, 256 threads
__global__ __launch_bounds__(256) void k_proj(
    const float* __restrict__ x, const float* __restrict__ W,
    const float* __restrict__ bW, const float* __restrict__ A1,
    const float* __restrict__ b1,
    float* __restrict__ h, float* __restrict__ hi, float* __restrict__ hjT)
{
    const int row0 = blockIdx.x * 8;     // global row (b*N + n)
    const int b    = row0 >> 9;
    const int rl0  = row0 & 511;
    const int tid  = threadIdx.x;

    __shared__ float xs[8 * F_IN];       // 8 KB
    __shared__ float hs[8 * F_OUT];      // 4 KB
    __shared__ float hjs[8 * HH];        // 2 KB

    #pragma unroll
    for (int t = 0; t < 8; ++t)
        xs[tid + t * 256] = x[(size_t)row0 * F_IN + tid + t * 256];
    __syncthreads();

    // ---- h = x @ W^T + bW : thread = (o = tid&127, row-half = tid>>7) ----
    {
        const int o  = tid & 127;
        const int rh = (tid >> 7) * 4;
        float acc[4];
        const float bv = bW[o];
        #pragma unroll
        for (int r = 0; r < 4; ++r) acc[r] = bv;
        const float4* wr = (const float4*)(W + (size_t)o * F_IN);
        #pragma unroll 4
        for (int f4 = 0; f4 < F_IN / 4; ++f4) {
            const float4 wv = wr[f4];
            #pragma unroll
            for (int r = 0; r < 4; ++r) {
                const float4 xv = *((const float4*)(xs + (rh + r) * F_IN) + f4);
                acc[r] = fmaf(xv.x, wv.x, acc[r]);
                acc[r] = fmaf(xv.y, wv.y, acc[r]);
                acc[r] = fmaf(xv.z, wv.z, acc[r]);
                acc[r] = fmaf(xv.w, wv.w, acc[r]);
            }
        }
        #pragma unroll
        for (int r = 0; r < 4; ++r) {
            h[((size_t)row0 + rh + r) * F_OUT + o] = acc[r];
            hs[(rh + r) * F_OUT + o] = acc[r];
        }
    }
    __syncthreads();

    // ---- hi'/hj : thread = (k = tid&63, half = (tid>>6)&1, row-half = tid>>7) ----
    {
        const int k    = tid & 63;
        const int half = (tid >> 6) & 1;
        const int rh   = (tid >> 7) * 4;
        float acc2[4];
        const float init = half ? 0.0f : b1[k];
        #pragma unroll
        for (int r = 0; r < 4; ++r) acc2[r] = init;
        const float4* ar = (const float4*)(A1 + (size_t)k * (2 * F_OUT) + half * F_OUT);
        #pragma unroll 4
        for (int o4 = 0; o4 < F_OUT / 4; ++o4) {
            const float4 av = ar[o4];
            #pragma unroll
            for (int r = 0; r < 4; ++r) {
                const float4 hv = *((const float4*)(hs + (rh + r) * F_OUT) + o4);
                acc2[r] = fmaf(hv.x, av.x, acc2[r]);
                acc2[r] = fmaf(hv.y, av.y, acc2[r]);
                acc2[r] = fmaf(hv.z, av.z, acc2[r]);
                acc2[r] = fmaf(hv.w, av.w, acc2[r]);
            }
        }
        if (half == 0) {
            #pragma unroll
            for (int r = 0; r < 4; ++r) hi[((size_t)row0 + rh + r) * HH + k] = acc2[r];
        } else {
            #pragma unroll
            for (int r = 0; r < 4; ++r) hjs[(rh + r) * HH + k] = acc2[r];
        }
    }
    __syncthreads();

    // ---- cooperative transposed store hjT[b][k][rl0 + r] ----
    {
        const int kk = tid >> 2;          // 0..63
        const int r0 = (tid & 3) * 2;     // 0,2,4,6
        float2 v;
        v.x = hjs[(r0 + 0) * HH + kk];
        v.y = hjs[(r0 + 1) * HH + kk];
        *(float2*)(hjT + ((size_t)b * HH + kk) * NN + rl0 + r0) = v;
    }
}

// K2: e-scores, 8 i-rows x 256 j per block; per-block softmax stats
__global__ __launch_bounds__(256) void k_scores(
    const float* __restrict__ hi, const float* __restrict__ hjT,
    const float* __restrict__ A2, const float* __restrict__ b2,
    const float* __restrict__ adj, float* __restrict__ e,
    float* __restrict__ stat_m, float* __restrict__ stat_s)
{
    const int blk = blockIdx.x;        // B * 64 * 2
    const int b   = blk >> 7;
    const int it  = (blk >> 1) & 63;
    const int i0  = it * 8;
    const int j   = (blk & 1) * 256 + threadIdx.x;
    const int tid = threadIdx.x;

    __shared__ float hib[8 * HH];      // 2 KB (hi + b1, per i-row)
    __shared__ float a2s[HH];
    __shared__ float wred[4];

    hib[tid]       = hi[((size_t)(b * NN) + i0) * HH + tid];
    hib[tid + 256] = hi[((size_t)(b * NN) + i0) * HH + tid + 256];
    if (tid < HH) a2s[tid] = A2[tid];
    __syncthreads();

    float s[8] = {0, 0, 0, 0, 0, 0, 0, 0};
    const float* hjb = hjT + (size_t)b * HH * NN;
    #pragma unroll 4
    for (int k4 = 0; k4 < HH; k4 += 4) {
        const float hj0 = hjb[(size_t)(k4 + 0) * NN + j];
        const float hj1 = hjb[(size_t)(k4 + 1) * NN + j];
        const float hj2 = hjb[(size_t)(k4 + 2) * NN + j];
        const float hj3 = hjb[(size_t)(k4 + 3) * NN + j];
        const float4 a2v = *(const float4*)(a2s + k4);
        #pragma unroll
        for (int r = 0; r < 8; ++r) {
            const float4 hv = *(const float4*)(hib + r * HH + k4);
            s[r] = fmaf(fmaxf(hv.x + hj0, 0.0f), a2v.x, s[r]);
            s[r] = fmaf(fmaxf(hv.y + hj1, 0.0f), a2v.y, s[r]);
            s[r] = fmaf(fmaxf(hv.z + hj2, 0.0f), a2v.z, s[r]);
            s[r] = fmaf(fmaxf(hv.w + hj3, 0.0f), a2v.w, s[r]);
        }
    }

    const float b2v = b2[0];
    float lmax = -INFINITY;
    #pragma unroll
    for (int r = 0; r < 8; ++r) {
        float v = s[r] + b2v;
        v = (v >= 0.0f) ? v : LALPHA * v;
        const float a = adj[((size_t)(b * NN) + i0 + r) * NN + j];
        v = (a != 0.0f) ? v : NEG_INF_F;
        e[((size_t)(b * NN) + i0 + r) * NN + j] = v;
        s[r] = v;
        lmax = fmaxf(lmax, v);
    }

    // block max
    float wm = lmax;
    #pragma unroll
    for (int off = 32; off; off >>= 1) wm = fmaxf(wm, __shfl_xor(wm, off, 64));
    if ((tid & 63) == 0) wred[tid >> 6] = wm;
    __syncthreads();
    const float m_blk = fmaxf(fmaxf(wred[0], wred[1]), fmaxf(wred[2], wred[3]));
    __syncthreads();

    // block sum of exp(e - m_blk)
    float ls = 0.0f;
    #pragma unroll
    for (int r = 0; r < 8; ++r) ls += expf(s[r] - m_blk);
    #pragma unroll
    for (int off = 32; off; off >>= 1) ls += __shfl_xor(ls, off, 64);
    if ((tid & 63) == 0) wred[tid >> 6] = ls;
    __syncthreads();
    if (tid == 0) {
        stat_m[blk] = m_blk;
        stat_s[blk] = wred[0] + wred[1] + wred[2] + wred[3];
    }
}

// K3: combine per-block stats -> global per-batch max M and sum S
__global__ __launch_bounds__(128) void k_reduce(
    const float* __restrict__ stat_m, const float* __restrict__ stat_s,
    float* __restrict__ Mg, float* __restrict__ Sg)
{
    const int b   = blockIdx.x;
    const int tid = threadIdx.x;
    __shared__ float sm[2], ss[2];

    const float m = stat_m[b * 128 + tid];
    float lm = m;
    #pragma unroll
    for (int off = 32; off; off >>= 1) lm = fmaxf(lm, __shfl_xor(lm, off, 64));
    if ((tid & 63) == 0) sm[tid >> 6] = lm;
    __syncthreads();
    const float M = fmaxf(sm[0], sm[1]);

    float sv = stat_s[b * 128 + tid] * expf(m - M);
    #pragma unroll
    for (int off = 32; off; off >>= 1) sv += __shfl_xor(sv, off, 64);
    if ((tid & 63) == 0) ss[tid >> 6] = sv;
    __syncthreads();
    if (tid == 0) { Mg[b] = M; Sg[b] = ss[0] + ss[1]; }
}

// K4: out = elu( (exp(e - M)/S) @ h ), exp fused into staging
// 8 i-rows x 128 o per block, 512 threads (4-way j split)
__global__ __launch_bounds__(512) void k_aggregate(
    const float* __restrict__ e, const float* __restrict__ h,
    const float* __restrict__ Mg, const float* __restrict__ Sg,
    float* __restrict__ out)
{
    const int blk = blockIdx.x;        // B * 64
    const int b   = blk >> 6;
    const int i0  = (blk & 63) * 8;
    const int tid = threadIdx.x;
    const int o   = tid & 127;
    const int p   = tid >> 7;          // 0..3

    const float M    = Mg[b];
    const float invS = 1.0f / Sg[b];

    __shared__ float wlsT[64][12];        // [jj][r], padded to 12 for b128 align
    __shared__ float red[4][8][F_OUT];    // 16 KB

    float acc[8] = {0, 0, 0, 0, 0, 0, 0, 0};
    const float* eb = e + ((size_t)(b * NN) + i0) * NN;
    const float* hb = h + (size_t)b * NN * F_OUT;

    for (int j0 = 0; j0 < NN; j0 += 64) {
        {   // stage + exp: 512 elems, 1 per thread
            const int jj = tid & 63, r = tid >> 6;
            wlsT[jj][r] = expf(eb[(size_t)r * NN + j0 + jj] - M);
        }
        __syncthreads();
        for (int jj = p; jj < 64; jj += 4) {
            const float hv = hb[(size_t)(j0 + jj) * F_OUT + o];
            const float4 w0 = *(const float4*)&wlsT[jj][0];
            const float4 w1 = *(const float4*)&wlsT[jj][4];
            acc[0] = fmaf(w0.x, hv, acc[0]);
            acc[1] = fmaf(w0.y, hv, acc[1]);
            acc[2] = fmaf(w0.z, hv, acc[2]);
            acc[3] = fmaf(w0.w, hv, acc[3]);
            acc[4] = fmaf(w1.x, hv, acc[4]);
            acc[5] = fmaf(w1.y, hv, acc[5]);
            acc[6] = fmaf(w1.z, hv, acc[6]);
            acc[7] = fmaf(w1.w, hv, acc[7]);
        }
        __syncthreads();
    }

    #pragma unroll
    for (int r = 0; r < 8; ++r) red[p][r][o] = acc[r];
    __syncthreads();
    #pragma unroll
    for (int t = 0; t < 2; ++t) {
        const int idx = tid + t * 512;        // 1024 outputs
        const int r = idx >> 7, oo = idx & 127;
        float sv = red[0][r][oo] + red[1][r][oo] + red[2][r][oo] + red[3][r][oo];
        sv *= invS;
        out[((size_t)(b * NN) + i0 + r) * F_OUT + oo] = (sv > 0.0f) ? sv : expm1f(sv);
    }
}

extern "C" void kernel_launch(void* const* d_in, const int* in_sizes, int n_in,
                              void* d_out, int out_size, void* d_ws, size_t ws_size,
                              hipStream_t stream) {
    const float* x   = (const float*)d_in[0];
    const float* adj = (const float*)d_in[1];
    const float* W   = (const float*)d_in[2];
    const float* bW  = (const float*)d_in[3];
    const float* A1  = (const float*)d_in[4];
    const float* b1  = (const float*)d_in[5];
    const float* A2  = (const float*)d_in[6];
    const float* b2  = (const float*)d_in[7];
    float* out = (float*)d_out;

    float* ws  = (float*)d_ws;
    float* h      = ws;                                   // 262144
    float* hi     = h   + (size_t)BB * NN * F_OUT;        // 131072
    float* hjT    = hi  + (size_t)BB * NN * HH;           // 131072
    float* e      = hjT + (size_t)BB * HH * NN;           // 1048576
    float* stat_m = e   + (size_t)BB * NN * NN;           // 512
    float* stat_s = stat_m + 512;                         // 512
    float* Mg     = stat_s + 512;                         // 4
    float* Sg     = Mg + 4;                               // 4

    k_proj     <<<BB * 64,      256, 0, stream>>>(x, W, bW, A1, b1, h, hi, hjT);
    k_scores   <<<BB * 64 * 2,  256, 0, stream>>>(hi, hjT, A2, b2, adj, e, stat_m, stat_s);
    k_reduce   <<<BB,           128, 0, stream>>>(stat_m, stat_s, Mg, Sg);
    k_aggregate<<<BB * 64,      512, 0, stream>>>(e, h, Mg, Sg, out);
}